// Round 3
// baseline (579.027 us; speedup 1.0000x reference)
//
#include <hip/hip_runtime.h>
#include <cstdint>
#include <cstddef>

typedef _Float16 half8 __attribute__((ext_vector_type(8)));
typedef _Float16 half4 __attribute__((ext_vector_type(4)));
typedef float f32x4 __attribute__((ext_vector_type(4)));

#define GAT_N 8192
#define GAT_F 256
#define GAT_NW 256   // adj bitmask words per row (8192/32)
#define GAT_ALPHA 0.2f
#define GAT_LOG2E 1.4426950408889634f

// Monotone float->uint encoding for atomicMax over floats of any sign.
__device__ inline unsigned enc_f32(float x) {
    unsigned b = __float_as_uint(x);
    return (b & 0x80000000u) ? ~b : (b | 0x80000000u);
}
__device__ inline float dec_f32(unsigned u) {
    unsigned b = (u & 0x80000000u) ? (u ^ 0x80000000u) : ~u;
    return __uint_as_float(b);
}

// ---------------------------------------------------------------------------
// K0a: bit-pack adj (int32 0/1, 268 MB) -> adjB (1 bit/edge, 8 MB).
// One wave per row; lane packs 8 consecutive keys into one byte.
// Byte b of a row covers keys [8b, 8b+8); bit j = key 8b+j.
// Pure streaming: 2048 blocks x 4 waves = 8192 waves (32/CU), int4 loads.
// ---------------------------------------------------------------------------
__global__ __launch_bounds__(256) void gat_k0_pack(
    const int* __restrict__ adj, unsigned char* __restrict__ adjB)
{
    const int wv = threadIdx.x >> 6;
    const int lane = threadIdx.x & 63;
    const int row = blockIdx.x * 4 + wv;
    const int* src = adj + (size_t)row * GAT_N;
    unsigned char* dst = adjB + (size_t)row * (GAT_N / 8);
    #pragma unroll 4
    for (int k = 0; k < 16; ++k) {
        const int4 v0 = *reinterpret_cast<const int4*>(src + k * 512 + lane * 8);
        const int4 v1 = *reinterpret_cast<const int4*>(src + k * 512 + lane * 8 + 4);
        unsigned m = (unsigned)(v0.x > 0)        | ((unsigned)(v0.y > 0) << 1)
                   | ((unsigned)(v0.z > 0) << 2) | ((unsigned)(v0.w > 0) << 3)
                   | ((unsigned)(v1.x > 0) << 4) | ((unsigned)(v1.y > 0) << 5)
                   | ((unsigned)(v1.z > 0) << 6) | ((unsigned)(v1.w > 0) << 7);
        dst[k * 64 + lane] = (unsigned char)m;
    }
}

// ---------------------------------------------------------------------------
// K0b: W -> fp16 transposed WT[n][k]; init encoded f2max.
// ---------------------------------------------------------------------------
__global__ __launch_bounds__(256) void gat_k0b_convert(
    const float* __restrict__ W, _Float16* __restrict__ WT,
    unsigned* __restrict__ f2mxEnc)
{
    const int g = blockIdx.x * 256 + threadIdx.x;      // 65536 threads
    if (g == 0) *f2mxEnc = 0u;                          // enc(-FLT_MAX)
    const int k = g >> 8, n = g & 255;
    WT[n * GAT_F + k] = (_Float16)W[g];
}

// ---------------------------------------------------------------------------
// K1: Wh = h @ W via fp16 MFMA (fp32 accum); h converted inline fp32->fp16.
// Epilogue: f1L = (Wh@a1)*log2(e), f2L = (Wh@a2)*log2(e) (leaky commutes with
// positive scale: leaky(x)*c = max(xc, 0.2xc)), atomicMax enc(f2L),
// whT[n][row] fp16. grid 256 x 2 waves (16 rows/wave, full 256 cols).
// ---------------------------------------------------------------------------
__global__ __launch_bounds__(128) void gat_k1_gemm(
    const float* __restrict__ h, const _Float16* __restrict__ WT,
    const float* __restrict__ a, _Float16* __restrict__ whT,
    float* __restrict__ f1L, float* __restrict__ f2L,
    unsigned* __restrict__ f2mxEnc)
{
    const int wv = threadIdx.x >> 6;
    const int lane = threadIdx.x & 63;
    const int l15 = lane & 15;
    const int quad = lane >> 4;
    const int r0 = blockIdx.x * 32 + wv * 16;

    f32x4 acc[16];
    #pragma unroll
    for (int t = 0; t < 16; ++t) { f32x4 z = {0.f,0.f,0.f,0.f}; acc[t] = z; }

    #pragma unroll
    for (int k0 = 0; k0 < GAT_F; k0 += 32) {
        const float* ap = h + (size_t)(r0 + l15) * GAT_F + k0 + quad * 8;
        const float4 a0 = *reinterpret_cast<const float4*>(ap);
        const float4 a1 = *reinterpret_cast<const float4*>(ap + 4);
        half8 af;
        af[0] = (_Float16)a0.x; af[1] = (_Float16)a0.y;
        af[2] = (_Float16)a0.z; af[3] = (_Float16)a0.w;
        af[4] = (_Float16)a1.x; af[5] = (_Float16)a1.y;
        af[6] = (_Float16)a1.z; af[7] = (_Float16)a1.w;
        #pragma unroll
        for (int t = 0; t < 16; ++t) {
            half8 bf = *reinterpret_cast<const half8*>(
                WT + (size_t)(t * 16 + l15) * GAT_F + k0 + quad * 8);
            acc[t] = __builtin_amdgcn_mfma_f32_16x16x32_f16(af, bf, acc[t], 0, 0, 0);
        }
    }

    // f1/f2 epilogue. Lane holds rows quad*4+reg, cols t*16+l15.
    float p1[4] = {0.f,0.f,0.f,0.f}, p2[4] = {0.f,0.f,0.f,0.f};
    #pragma unroll
    for (int t = 0; t < 16; ++t) {
        float a1c = a[t * 16 + l15];
        float a2c = a[GAT_F + t * 16 + l15];
        #pragma unroll
        for (int r = 0; r < 4; ++r) {
            p1[r] = fmaf(acc[t][r], a1c, p1[r]);
            p2[r] = fmaf(acc[t][r], a2c, p2[r]);
        }
    }
    #pragma unroll
    for (int off = 1; off < 16; off <<= 1) {
        #pragma unroll
        for (int r = 0; r < 4; ++r) {
            p1[r] += __shfl_xor(p1[r], off);
            p2[r] += __shfl_xor(p2[r], off);
        }
    }
    if (l15 == 0) {
        float mx = -3.0e38f;
        #pragma unroll
        for (int r = 0; r < 4; ++r) {
            int row = r0 + quad * 4 + r;
            float s1 = p1[r] * GAT_LOG2E;
            float s2 = p2[r] * GAT_LOG2E;
            f1L[row] = s1;
            f2L[row] = s2;
            mx = fmaxf(mx, s2);
        }
        atomicMax(f2mxEnc, enc_f32(mx));
    }

    // whT[n][row] fp16: lane stores 4 consecutive rows per col-tile.
    #pragma unroll
    for (int t = 0; t < 16; ++t) {
        half4 hv;
        #pragma unroll
        for (int r = 0; r < 4; ++r) hv[r] = (_Float16)acc[t][r];
        *reinterpret_cast<half4*>(
            whT + (size_t)(t * 16 + l15) * GAT_N + r0 + quad * 4) = hv;
    }
}

// ---------------------------------------------------------------------------
// K3: fused masked softmax-numerator x V via fp16 MFMA, bitmask adjacency.
// grid = 64 row-groups x 8 key-slices = 512 blocks, 2 blocks/CU.
// Wave: 32 rows x 256 feats, 1024-key slice (32 steps of 32 keys).
// adj: one uint32 word per row per step, loaded as uint4 per 4-step group,
// prefetched a full group ahead (in-flight >> L3 latency). f2 prefetched
// 1 step ahead (L1-hot 4 KB slice). B-frags from L2-resident whT.
// ---------------------------------------------------------------------------
__global__ __launch_bounds__(256, 2) void gat_k3_attn(
    const unsigned* __restrict__ adjW, const float* __restrict__ f1L,
    const float* __restrict__ f2L, const unsigned* __restrict__ f2mxEnc,
    const _Float16* __restrict__ whT,
    _Float16* __restrict__ Ph,     // 8 slabs x 8192x256 fp16, permuted
    float* __restrict__ L)         // [8][8192]
{
    const int bx = blockIdx.x;
    const int rb = bx >> 3;          // row group 0..63
    const int q  = bx & 7;           // key slice 0..7
    const int wv = threadIdx.x >> 6;
    const int lane = threadIdx.x & 63;
    const int l15 = lane & 15;
    const int quad = lane >> 4;

    const int r0 = rb * 128 + wv * 32;
    const int rA = r0 + l15;
    const int rB = rA + 16;

    const float fmxL = dec_f32(*f2mxEnc);
    const float f1A = f1L[rA];
    const float f1B = f1L[rB];
    const float sA = f1A + fmxL;
    const float sB = f1B + fmxL;
    const float CA = fmaxf(sA, GAT_ALPHA * sA);
    const float CB = fmaxf(sB, GAT_ALPHA * sB);

    f32x4 acc[2][16];
    #pragma unroll
    for (int s = 0; s < 2; ++s)
        #pragma unroll
        for (int t = 0; t < 16; ++t) {
            f32x4 z = {0.f,0.f,0.f,0.f};
            acc[s][t] = z;
        }
    float d0 = 0.f, d1 = 0.f;

    const int kq = q * 1024;
    const uint4* awA = reinterpret_cast<const uint4*>(adjW + (size_t)rA * GAT_NW + q * 32);
    const uint4* awB = reinterpret_cast<const uint4*>(adjW + (size_t)rB * GAT_NW + q * 32);
    const _Float16* wbase = whT + (size_t)l15 * GAT_N;
    const float* f2q = f2L + kq + quad * 8;

    uint4 nA = awA[0];
    uint4 nB = awB[0];
    float4 nfa = *reinterpret_cast<const float4*>(f2q);
    float4 nfb = *reinterpret_cast<const float4*>(f2q + 4);

    for (int g = 0; g < 8; ++g) {
        const uint4 cA = nA, cB = nB;
        if (g < 7) { nA = awA[g + 1]; nB = awB[g + 1]; }
        const unsigned wordsA[4] = {cA.x, cA.y, cA.z, cA.w};
        const unsigned wordsB[4] = {cB.x, cB.y, cB.z, cB.w};

        #pragma unroll
        for (int s4 = 0; s4 < 4; ++s4) {
            const int step = g * 4 + s4;
            const float4 cfa = nfa, cfb = nfb;
            if (step < 31) {
                nfa = *reinterpret_cast<const float4*>(f2q + (step + 1) * 32);
                nfb = *reinterpret_cast<const float4*>(f2q + (step + 1) * 32 + 4);
            }
            const unsigned mA = (wordsA[s4] >> (quad * 8)) & 0xffu;
            const unsigned mB = (wordsB[s4] >> (quad * 8)) & 0xffu;
            const float f2v[8] = {cfa.x, cfa.y, cfa.z, cfa.w, cfb.x, cfb.y, cfb.z, cfb.w};

            half8 pA, pB;
            #pragma unroll
            for (int j = 0; j < 8; ++j) {
                const float f2j = f2v[j];
                float xa = f1A + f2j;
                float la = fmaxf(xa, GAT_ALPHA * xa);
                float pa = __builtin_amdgcn_exp2f(la - CA);
                pa = (mA & (1u << j)) ? pa : 0.f;
                d0 += pa;
                pA[j] = (_Float16)pa;
                float xb = f1B + f2j;
                float lb = fmaxf(xb, GAT_ALPHA * xb);
                float pb = __builtin_amdgcn_exp2f(lb - CB);
                pb = (mB & (1u << j)) ? pb : 0.f;
                d1 += pb;
                pB[j] = (_Float16)pb;
            }

            const int kb = kq + step * 32 + quad * 8;
            #pragma unroll
            for (int t = 0; t < 16; ++t) {
                half8 bf = *reinterpret_cast<const half8*>(
                    wbase + (size_t)t * 16 * GAT_N + kb);
                acc[0][t] = __builtin_amdgcn_mfma_f32_16x16x32_f16(pA, bf, acc[0][t], 0, 0, 0);
                acc[1][t] = __builtin_amdgcn_mfma_f32_16x16x32_f16(pB, bf, acc[1][t], 0, 0, 0);
            }
        }
    }

    // Row denominators: reduce over quads (all lanes end with full row sum).
    d0 += __shfl_xor(d0, 16); d0 += __shfl_xor(d0, 32);
    d1 += __shfl_xor(d1, 16); d1 += __shfl_xor(d1, 32);
    float* Lq = L + q * GAT_N;
    if (lane < 16) { Lq[rA] = d0; Lq[rB] = d1; }

    // Coalesced permuted fp16 partial store: wave-chunk of 8192 halves.
    const int wid = rb * 4 + wv;                       // 0..255
    _Float16* Pq = Ph + ((size_t)q * 256 + wid) * 8192;
    #pragma unroll
    for (int s = 0; s < 2; ++s)
        #pragma unroll
        for (int t = 0; t < 16; ++t) {
            half4 hv;
            #pragma unroll
            for (int r = 0; r < 4; ++r) hv[r] = (_Float16)acc[s][t][r];
            *reinterpret_cast<half4*>(Pq + (size_t)(((s * 16 + t) * 64 + lane) * 4)) = hv;
        }
}

// ---------------------------------------------------------------------------
// K4: un-permute + combine 8 fp16 partials, normalize, ELU, write out.
// ---------------------------------------------------------------------------
__global__ __launch_bounds__(256) void gat_k4_final(
    const _Float16* __restrict__ Ph, const float* __restrict__ L,
    float* __restrict__ out)
{
    const int tid = threadIdx.x;
    const int wid = blockIdx.x >> 3;                   // wave-chunk 0..255
    __shared__ float s_rl[32];
    if (tid < 32) {
        const int row = wid * 32 + tid;
        float s = 0.f;
        #pragma unroll
        for (int q = 0; q < 8; ++q) s += L[q * GAT_N + row];
        s_rl[tid] = 1.0f / fmaxf(s, 1e-30f);
    }
    __syncthreads();

    const int idx = blockIdx.x * 256 + tid;            // half4 position
    const int rem = idx & 2047;                        // within wave-chunk
    const int lane = rem & 63;
    const int st = rem >> 6;
    const int s = st >> 4, t = st & 15;
    const int l15 = lane & 15, quad = lane >> 4;
    const int lrow0 = s * 16 + quad * 4;               // local rows lrow0..+3
    const int col = t * 16 + l15;

    float accv[4] = {0.f, 0.f, 0.f, 0.f};
    #pragma unroll
    for (int q = 0; q < 8; ++q) {
        half4 v = *reinterpret_cast<const half4*>(
            Ph + ((size_t)q * 256 + wid) * 8192 + (size_t)rem * 4);
        #pragma unroll
        for (int r = 0; r < 4; ++r) accv[r] += (float)v[r];
    }
    #pragma unroll
    for (int r = 0; r < 4; ++r) {
        const float v = accv[r] * s_rl[lrow0 + r];
        const float o = v > 0.f ? v : expm1f(v);
        out[(size_t)(wid * 32 + lrow0 + r) * GAT_F + col] = o;
    }
}

// ---------------------------------------------------------------------------
extern "C" void kernel_launch(void* const* d_in, const int* in_sizes, int n_in,
                              void* d_out, int out_size, void* d_ws, size_t ws_size,
                              hipStream_t stream)
{
    const float* h   = (const float*)d_in[0];
    const int*   adj = (const int*)d_in[1];
    // d_in[2] = cv_values: constant per softmax row -> cancels exactly; unused.
    const float* W   = (const float*)d_in[3];
    const float* a   = (const float*)d_in[4];
    float* out = (float*)d_out;
    char* ws = (char*)d_ws;

    const size_t SLAB = (size_t)GAT_N * GAT_F * 2;     // 4 MiB (fp16 matrix)

    size_t off = 0;
    _Float16* whT = (_Float16*)(ws + off); off += SLAB;            // 4 MiB
    _Float16* Ph  = (_Float16*)(ws + off); off += 8 * SLAB;        // 32 MiB
    unsigned char* adjB = (unsigned char*)(ws + off); off += (size_t)GAT_N * GAT_N / 8; // 8 MiB
    _Float16* WT  = (_Float16*)(ws + off); off += (size_t)GAT_F * GAT_F * 2;            // 128 KiB
    float* f1L = (float*)(ws + off); off += GAT_N * 4;
    float* f2L = (float*)(ws + off); off += GAT_N * 4;
    float* L   = (float*)(ws + off); off += 8 * GAT_N * 4;
    unsigned* f2mxEnc = (unsigned*)(ws + off); off += 256;

    gat_k0_pack<<<2048, 256, 0, stream>>>(adj, adjB);
    gat_k0b_convert<<<256, 256, 0, stream>>>(W, WT, f2mxEnc);
    gat_k1_gemm<<<256, 128, 0, stream>>>(h, WT, a, whT, f1L, f2L, f2mxEnc);
    gat_k3_attn<<<512, 256, 0, stream>>>((const unsigned*)adjB, f1L, f2L, f2mxEnc, whT, Ph, L);
    gat_k4_final<<<2048, 256, 0, stream>>>(Ph, L, out);
}

// Round 4
// 481.211 us; speedup vs baseline: 1.2033x; 1.2033x over previous
//
#include <hip/hip_runtime.h>
#include <cstdint>
#include <cstddef>

typedef _Float16 half8 __attribute__((ext_vector_type(8)));
typedef _Float16 half4 __attribute__((ext_vector_type(4)));
typedef float f32x4 __attribute__((ext_vector_type(4)));

#define GAT_N 8192
#define GAT_F 256
#define GAT_NW 256   // adj bitmask words per row (8192/32)
#define GAT_ALPHA 0.2f
#define GAT_LOG2E 1.4426950408889634f

// Monotone float->uint encoding for atomicMax over floats of any sign.
__device__ inline unsigned enc_f32(float x) {
    unsigned b = __float_as_uint(x);
    return (b & 0x80000000u) ? ~b : (b | 0x80000000u);
}
__device__ inline float dec_f32(unsigned u) {
    unsigned b = (u & 0x80000000u) ? (u ^ 0x80000000u) : ~u;
    return __uint_as_float(b);
}

// ---------------------------------------------------------------------------
// K0a: bit-pack adj (int32 0/1, 268 MB) -> adjB (1 bit/edge, 8 MB).
// One wave per row; byte b of a row covers keys [8b, 8b+8), bit j = key 8b+j.
// ---------------------------------------------------------------------------
__global__ __launch_bounds__(256) void gat_k0_pack(
    const int* __restrict__ adj, unsigned char* __restrict__ adjB)
{
    const int wv = threadIdx.x >> 6;
    const int lane = threadIdx.x & 63;
    const int row = blockIdx.x * 4 + wv;
    const int* src = adj + (size_t)row * GAT_N;
    unsigned char* dst = adjB + (size_t)row * (GAT_N / 8);
    #pragma unroll 4
    for (int k = 0; k < 16; ++k) {
        const int4 v0 = *reinterpret_cast<const int4*>(src + k * 512 + lane * 8);
        const int4 v1 = *reinterpret_cast<const int4*>(src + k * 512 + lane * 8 + 4);
        unsigned m = (unsigned)(v0.x > 0)        | ((unsigned)(v0.y > 0) << 1)
                   | ((unsigned)(v0.z > 0) << 2) | ((unsigned)(v0.w > 0) << 3)
                   | ((unsigned)(v1.x > 0) << 4) | ((unsigned)(v1.y > 0) << 5)
                   | ((unsigned)(v1.z > 0) << 6) | ((unsigned)(v1.w > 0) << 7);
        dst[k * 64 + lane] = (unsigned char)m;
    }
}

// ---------------------------------------------------------------------------
// K0b: W -> fp16 transposed WT[n][k]; init encoded f2max.
// ---------------------------------------------------------------------------
__global__ __launch_bounds__(256) void gat_k0b_convert(
    const float* __restrict__ W, _Float16* __restrict__ WT,
    unsigned* __restrict__ f2mxEnc)
{
    const int g = blockIdx.x * 256 + threadIdx.x;      // 65536 threads
    if (g == 0) *f2mxEnc = 0u;                          // enc(-FLT_MAX)
    const int k = g >> 8, n = g & 255;
    WT[n * GAT_F + k] = (_Float16)W[g];
}

// ---------------------------------------------------------------------------
// K1: Wh = h @ W via fp16 MFMA (fp32 accum); h converted inline fp32->fp16.
// Epilogue: f1L=(Wh@a1)*log2e, f2L=(Wh@a2)*log2e, atomicMax enc(f2L),
// whT[n][row] fp16. grid 256 x 2 waves (16 rows/wave, full 256 cols).
// ---------------------------------------------------------------------------
__global__ __launch_bounds__(128) void gat_k1_gemm(
    const float* __restrict__ h, const _Float16* __restrict__ WT,
    const float* __restrict__ a, _Float16* __restrict__ whT,
    float* __restrict__ f1L, float* __restrict__ f2L,
    unsigned* __restrict__ f2mxEnc)
{
    const int wv = threadIdx.x >> 6;
    const int lane = threadIdx.x & 63;
    const int l15 = lane & 15;
    const int quad = lane >> 4;
    const int r0 = blockIdx.x * 32 + wv * 16;

    f32x4 acc[16];
    #pragma unroll
    for (int t = 0; t < 16; ++t) { f32x4 z = {0.f,0.f,0.f,0.f}; acc[t] = z; }

    #pragma unroll
    for (int k0 = 0; k0 < GAT_F; k0 += 32) {
        const float* ap = h + (size_t)(r0 + l15) * GAT_F + k0 + quad * 8;
        const float4 a0 = *reinterpret_cast<const float4*>(ap);
        const float4 a1 = *reinterpret_cast<const float4*>(ap + 4);
        half8 af;
        af[0] = (_Float16)a0.x; af[1] = (_Float16)a0.y;
        af[2] = (_Float16)a0.z; af[3] = (_Float16)a0.w;
        af[4] = (_Float16)a1.x; af[5] = (_Float16)a1.y;
        af[6] = (_Float16)a1.z; af[7] = (_Float16)a1.w;
        #pragma unroll
        for (int t = 0; t < 16; ++t) {
            half8 bf = *reinterpret_cast<const half8*>(
                WT + (size_t)(t * 16 + l15) * GAT_F + k0 + quad * 8);
            acc[t] = __builtin_amdgcn_mfma_f32_16x16x32_f16(af, bf, acc[t], 0, 0, 0);
        }
    }

    float p1[4] = {0.f,0.f,0.f,0.f}, p2[4] = {0.f,0.f,0.f,0.f};
    #pragma unroll
    for (int t = 0; t < 16; ++t) {
        float a1c = a[t * 16 + l15];
        float a2c = a[GAT_F + t * 16 + l15];
        #pragma unroll
        for (int r = 0; r < 4; ++r) {
            p1[r] = fmaf(acc[t][r], a1c, p1[r]);
            p2[r] = fmaf(acc[t][r], a2c, p2[r]);
        }
    }
    #pragma unroll
    for (int off = 1; off < 16; off <<= 1) {
        #pragma unroll
        for (int r = 0; r < 4; ++r) {
            p1[r] += __shfl_xor(p1[r], off);
            p2[r] += __shfl_xor(p2[r], off);
        }
    }
    if (l15 == 0) {
        float mx = -3.0e38f;
        #pragma unroll
        for (int r = 0; r < 4; ++r) {
            int row = r0 + quad * 4 + r;
            float s1 = p1[r] * GAT_LOG2E;
            float s2 = p2[r] * GAT_LOG2E;
            f1L[row] = s1;
            f2L[row] = s2;
            mx = fmaxf(mx, s2);
        }
        atomicMax(f2mxEnc, enc_f32(mx));
    }

    #pragma unroll
    for (int t = 0; t < 16; ++t) {
        half4 hv;
        #pragma unroll
        for (int r = 0; r < 4; ++r) hv[r] = (_Float16)acc[t][r];
        *reinterpret_cast<half4*>(
            whT + (size_t)(t * 16 + l15) * GAT_N + r0 + quad * 4) = hv;
    }
}

// ---------------------------------------------------------------------------
// K3: fused masked softmax-numerator x V via fp16 MFMA, bitmask adjacency,
// LDS-staged B-tiles (double-buffered global_load_lds, width=16).
// grid = 64 row-groups x 8 key-slices = 512 blocks, 2 blocks/CU.
// Per step the block stages the shared 32-key x 256-feat whT tile (16 KB)
// into LDS while computing on the other buffer; waves read B-frags via
// ds_read_b128. adj: uint4 per 4 steps; f2: 1-step register prefetch.
// ---------------------------------------------------------------------------
__global__ __launch_bounds__(256, 2) void gat_k3_attn(
    const unsigned* __restrict__ adjW, const float* __restrict__ f1L,
    const float* __restrict__ f2L, const unsigned* __restrict__ f2mxEnc,
    const _Float16* __restrict__ whT,
    _Float16* __restrict__ Ph,     // 8 slabs x 8192x256 fp16, permuted
    float* __restrict__ L)         // [8][8192]
{
    __shared__ __align__(16) _Float16 sB[2][256 * 32];  // [buf][feat*32+key]

    const int bx = blockIdx.x;
    const int rb = bx >> 3;          // row group 0..63
    const int q  = bx & 7;           // key slice 0..7 (bx%8 ~ XCD)
    const int wv = threadIdx.x >> 6;
    const int lane = threadIdx.x & 63;
    const int l15 = lane & 15;
    const int quad = lane >> 4;

    const int r0 = rb * 128 + wv * 32;
    const int rA = r0 + l15;
    const int rB = rA + 16;

    const float fmxL = dec_f32(*f2mxEnc);
    const float f1A = f1L[rA];
    const float f1B = f1L[rB];
    const float sA = f1A + fmxL;
    const float sBv = f1B + fmxL;
    const float CA = fmaxf(sA, GAT_ALPHA * sA);
    const float CB = fmaxf(sBv, GAT_ALPHA * sBv);

    f32x4 acc[2][16];
    #pragma unroll
    for (int s = 0; s < 2; ++s)
        #pragma unroll
        for (int t = 0; t < 16; ++t) {
            f32x4 z = {0.f,0.f,0.f,0.f};
            acc[s][t] = z;
        }
    float d0 = 0.f, d1 = 0.f;

    const int kq = q * 1024;
    const uint4* awA = reinterpret_cast<const uint4*>(adjW + (size_t)rA * GAT_NW + q * 32);
    const uint4* awB = reinterpret_cast<const uint4*>(adjW + (size_t)rB * GAT_NW + q * 32);
    const float* f2q = f2L + kq + quad * 8;

    // Stage step tile into buf: wave wv covers feats [wv*64, wv*64+64).
    // Lane i loads 16 B: feat wv*64+i*16+(i>>2-part), keys (i&3)*8..+8.
    const int sf = wv * 64 + (lane >> 2);               // staging feat (base)
    const int sk = (lane & 3) * 8;                      // staging key offset
    const _Float16* gstage = whT + (size_t)sf * GAT_N + kq + sk;

    #define STAGE(buf, step)                                                   \
        {                                                                      \
            _Float16* lp = &sB[buf][(wv * 64) * 32];                           \
            const _Float16* gp = gstage + (step) * 32;                         \
            _Pragma("unroll")                                                  \
            for (int i = 0; i < 4; ++i) {                                      \
                __builtin_amdgcn_global_load_lds(                              \
                    (const __attribute__((address_space(1))) void*)            \
                        (gp + (size_t)i * 16 * GAT_N),                         \
                    (__attribute__((address_space(3))) void*)(lp + i * 512),   \
                    16, 0, 0);                                                 \
            }                                                                  \
        }

    STAGE(0, 0)
    uint4 nA = awA[0];
    uint4 nB = awB[0];
    float4 nfa = *reinterpret_cast<const float4*>(f2q);
    float4 nfb = *reinterpret_cast<const float4*>(f2q + 4);
    __syncthreads();   // buf0 staged (vmcnt drained by barrier semantics)

    for (int g = 0; g < 8; ++g) {
        const uint4 cA = nA, cB = nB;
        if (g < 7) { nA = awA[g + 1]; nB = awB[g + 1]; }

        #pragma unroll
        for (int s4 = 0; s4 < 4; ++s4) {
            const int step = g * 4 + s4;
            const int cur = step & 1;
            if (step + 1 < 32) STAGE(1 - cur, step + 1)

            const float4 cfa = nfa, cfb = nfb;
            if (step < 31) {
                nfa = *reinterpret_cast<const float4*>(f2q + (step + 1) * 32);
                nfb = *reinterpret_cast<const float4*>(f2q + (step + 1) * 32 + 4);
            }
            const unsigned wA = (s4 == 0) ? cA.x : (s4 == 1) ? cA.y : (s4 == 2) ? cA.z : cA.w;
            const unsigned wB = (s4 == 0) ? cB.x : (s4 == 1) ? cB.y : (s4 == 2) ? cB.z : cB.w;
            const unsigned mA = (wA >> (quad * 8)) & 0xffu;
            const unsigned mB = (wB >> (quad * 8)) & 0xffu;
            const float f2v[8] = {cfa.x, cfa.y, cfa.z, cfa.w, cfb.x, cfb.y, cfb.z, cfb.w};

            half8 pA, pB;
            #pragma unroll
            for (int j = 0; j < 8; ++j) {
                const float f2j = f2v[j];
                float xa = f1A + f2j;
                float la = fmaxf(xa, GAT_ALPHA * xa);
                float pa = __builtin_amdgcn_exp2f(la - CA);
                pa = (mA & (1u << j)) ? pa : 0.f;
                d0 += pa;
                pA[j] = (_Float16)pa;
                float xb = f1B + f2j;
                float lb = fmaxf(xb, GAT_ALPHA * xb);
                float pb = __builtin_amdgcn_exp2f(lb - CB);
                pb = (mB & (1u << j)) ? pb : 0.f;
                d1 += pb;
                pB[j] = (_Float16)pb;
            }

            #pragma unroll
            for (int t = 0; t < 16; ++t) {
                half8 bf = *reinterpret_cast<const half8*>(
                    &sB[cur][(t * 16 + l15) * 32 + quad * 8]);
                acc[0][t] = __builtin_amdgcn_mfma_f32_16x16x32_f16(pA, bf, acc[0][t], 0, 0, 0);
                acc[1][t] = __builtin_amdgcn_mfma_f32_16x16x32_f16(pB, bf, acc[1][t], 0, 0, 0);
            }
            __syncthreads();   // drains stage(step+1) + this step's ds_reads
        }
    }
    #undef STAGE

    // Row denominators: reduce over quads (all lanes end with full row sum).
    d0 += __shfl_xor(d0, 16); d0 += __shfl_xor(d0, 32);
    d1 += __shfl_xor(d1, 16); d1 += __shfl_xor(d1, 32);
    float* Lq = L + q * GAT_N;
    if (lane < 16) { Lq[rA] = d0; Lq[rB] = d1; }

    // Coalesced permuted fp16 partial store: wave-chunk of 8192 halves.
    const int wid = rb * 4 + wv;                       // 0..255
    _Float16* Pq = Ph + ((size_t)q * 256 + wid) * 8192;
    #pragma unroll
    for (int s = 0; s < 2; ++s)
        #pragma unroll
        for (int t = 0; t < 16; ++t) {
            half4 hv;
            #pragma unroll
            for (int r = 0; r < 4; ++r) hv[r] = (_Float16)acc[s][t][r];
            *reinterpret_cast<half4*>(Pq + (size_t)(((s * 16 + t) * 64 + lane) * 4)) = hv;
        }
}

// ---------------------------------------------------------------------------
// K4: un-permute + combine 8 fp16 partials, normalize, ELU, write out.
// ---------------------------------------------------------------------------
__global__ __launch_bounds__(256) void gat_k4_final(
    const _Float16* __restrict__ Ph, const float* __restrict__ L,
    float* __restrict__ out)
{
    const int tid = threadIdx.x;
    const int wid = blockIdx.x >> 3;                   // wave-chunk 0..255
    __shared__ float s_rl[32];
    if (tid < 32) {
        const int row = wid * 32 + tid;
        float s = 0.f;
        #pragma unroll
        for (int q = 0; q < 8; ++q) s += L[q * GAT_N + row];
        s_rl[tid] = 1.0f / fmaxf(s, 1e-30f);
    }
    __syncthreads();

    const int idx = blockIdx.x * 256 + tid;            // half4 position
    const int rem = idx & 2047;                        // within wave-chunk
    const int lane = rem & 63;
    const int st = rem >> 6;
    const int s = st >> 4, t = st & 15;
    const int l15 = lane & 15, quad = lane >> 4;
    const int lrow0 = s * 16 + quad * 4;               // local rows lrow0..+3
    const int col = t * 16 + l15;

    float accv[4] = {0.f, 0.f, 0.f, 0.f};
    #pragma unroll
    for (int q = 0; q < 8; ++q) {
        half4 v = *reinterpret_cast<const half4*>(
            Ph + ((size_t)q * 256 + wid) * 8192 + (size_t)rem * 4);
        #pragma unroll
        for (int r = 0; r < 4; ++r) accv[r] += (float)v[r];
    }
    #pragma unroll
    for (int r = 0; r < 4; ++r) {
        const float v = accv[r] * s_rl[lrow0 + r];
        const float o = v > 0.f ? v : expm1f(v);
        out[(size_t)(wid * 32 + lrow0 + r) * GAT_F + col] = o;
    }
}

// ---------------------------------------------------------------------------
extern "C" void kernel_launch(void* const* d_in, const int* in_sizes, int n_in,
                              void* d_out, int out_size, void* d_ws, size_t ws_size,
                              hipStream_t stream)
{
    const float* h   = (const float*)d_in[0];
    const int*   adj = (const int*)d_in[1];
    // d_in[2] = cv_values: constant per softmax row -> cancels exactly; unused.
    const float* W   = (const float*)d_in[3];
    const float* a   = (const float*)d_in[4];
    float* out = (float*)d_out;
    char* ws = (char*)d_ws;

    const size_t SLAB = (size_t)GAT_N * GAT_F * 2;     // 4 MiB (fp16 matrix)

    size_t off = 0;
    _Float16* whT = (_Float16*)(ws + off); off += SLAB;            // 4 MiB
    _Float16* Ph  = (_Float16*)(ws + off); off += 8 * SLAB;        // 32 MiB
    unsigned char* adjB = (unsigned char*)(ws + off); off += (size_t)GAT_N * GAT_N / 8; // 8 MiB
    _Float16* WT  = (_Float16*)(ws + off); off += (size_t)GAT_F * GAT_F * 2;            // 128 KiB
    float* f1L = (float*)(ws + off); off += GAT_N * 4;
    float* f2L = (float*)(ws + off); off += GAT_N * 4;
    float* L   = (float*)(ws + off); off += 8 * GAT_N * 4;
    unsigned* f2mxEnc = (unsigned*)(ws + off); off += 256;

    gat_k0_pack<<<2048, 256, 0, stream>>>(adj, adjB);
    gat_k0b_convert<<<256, 256, 0, stream>>>(W, WT, f2mxEnc);
    gat_k1_gemm<<<256, 128, 0, stream>>>(h, WT, a, whT, f1L, f2L, f2mxEnc);
    gat_k3_attn<<<512, 256, 0, stream>>>((const unsigned*)adjB, f1L, f2L, f2mxEnc, whT, Ph, L);
    gat_k4_final<<<2048, 256, 0, stream>>>(Ph, L, out);
}